// Round 1
// baseline (181.182 us; speedup 1.0000x reference)
//
#include <hip/hip_runtime.h>
#include <cmath>

// Problem constants (from reference setup_inputs)
constexpr int kB = 32;   // batch
constexpr int kA = 3;    // anchors
constexpr int kH = 64;
constexpr int kW = 64;
constexpr int kC = 85;
constexpr int kN = 64;   // targets per sample
constexpr int kCells = kA * kH * kW;                 // 12288 cells per sample
constexpr int kBlock = 256;
constexpr int kCellsPerThread = 2;
constexpr int kCellsPerBlock = kBlock * kCellsPerThread;   // 512
constexpr int kBlocksPerSample = kCells / kCellsPerBlock;  // 24
constexpr int kGridMain = kB * kBlocksPerSample;           // 768
constexpr int kWordsPerBlock = kCellsPerBlock / 32;        // 16
constexpr float kThreshold = 0.5f;
constexpr float kNoObjW = 0.5f;

// d_ws layout:
//   [0, kGridMain) : float per-block partial sums (plain stores overwrite poison)

// ---------------------------------------------------------------------------
// Fused kernel: per block, (a) recompute which targets land in THIS block's
// 512-cell slice (redundant per block but trivially cheap: 64 targets x 3
// anchors of IOU math), (b) BCE over the slice, (c) per-block partial sum.
// Eliminates the separate mark_kernel dispatch and the global bitmap
// round-trip entirely.
// ---------------------------------------------------------------------------
__global__ __launch_bounds__(kBlock) void fused_kernel(
    const float* __restrict__ output,   // (B,A,H,W,C)
    const float* __restrict__ targets,  // (B,N,5)
    const float* __restrict__ anchors,  // (A,2)
    float* __restrict__ partials)       // (kGridMain)
{
    __shared__ unsigned int bm[kWordsPerBlock];  // 512-bit gt slice
    __shared__ float red[kBlock / 64];

    const int blk   = blockIdx.x;
    const int b     = blk / kBlocksPerSample;
    const int cell0 = (blk % kBlocksPerSample) * kCellsPerBlock;
    const int tid   = threadIdx.x;

    if (tid < kWordsPerBlock) bm[tid] = 0u;
    __syncthreads();

    // Issue the two strided p-loads now; their HBM latency overlaps the
    // IOU/argmax math below (the pre-barrier vmcnt drain lands after it).
    const float* pbase =
        output + (size_t)b * kCells * kC + (size_t)(cell0 + tid) * kC + 4;
    float p0 = pbase[0];
    float p1 = pbase[(size_t)kBlock * kC];

    if (tid < kN) {  // one target per lane of the first wave
        const float* t = targets + ((size_t)b * kN + tid) * 5;
        float x = t[1], y = t[2], w = t[3], h = t[4];
        bool valid = !(x == 0.0f && y == 0.0f && w == 0.0f && h == 0.0f);

        float tx = x * kW, ty = y * kH, tw = w * kW, th = h * kH;
        float cx = floorf(tx), cy = floorf(ty);
        float zx = tx - (cx + 0.5f), zy = ty - (cy + 0.5f);

        float t_x0 = zx - tw * 0.5f, t_y0 = zy - th * 0.5f;
        float t_x1 = zx + tw * 0.5f, t_y1 = zy + th * 0.5f;
        float area_t = tw * th;

        float best = -1.0f;
        int aidx = 0;
        #pragma unroll
        for (int a = 0; a < kA; ++a) {
            float aw = anchors[a * 2 + 0], ah = anchors[a * 2 + 1];
            float x0 = fmaxf(t_x0, -aw * 0.5f);
            float y0 = fmaxf(t_y0, -ah * 0.5f);
            float x1 = fminf(t_x1,  aw * 0.5f);
            float y1 = fminf(t_y1,  ah * 0.5f);
            float inter = ((x0 < x1) && (y0 < y1)) ? (x1 - x0) * (y1 - y0) : 0.0f;
            float iou = inter / (area_t + aw * ah - inter);
            if (iou > best) { best = iou; aidx = a; }  // first-max wins (jnp.argmax)
        }
        if (valid && best > kThreshold) {
            int cxi = min(max((int)cx, 0), kW - 1);
            int cyi = min(max((int)cy, 0), kH - 1);
            int cell = aidx * (kH * kW) + cyi * kW + cxi;
            int local = cell - cell0;
            if ((unsigned)local < (unsigned)kCellsPerBlock)
                atomicOr(&bm[local >> 5], 1u << (local & 31));
        }
    }
    __syncthreads();

    const int l0 = tid, l1 = tid + kBlock;
    bool g0 = (bm[l0 >> 5] >> (l0 & 31)) & 1u;
    bool g1 = (bm[l1 >> 5] >> (l1 & 31)) & 1u;

    float acc =
        (g0 ? -fmaxf(logf(p0), -100.0f) : -kNoObjW * fmaxf(log1pf(-p0), -100.0f)) +
        (g1 ? -fmaxf(logf(p1), -100.0f) : -kNoObjW * fmaxf(log1pf(-p1), -100.0f));

    #pragma unroll
    for (int off = 32; off > 0; off >>= 1)
        acc += __shfl_down(acc, off, 64);
    if ((tid & 63) == 0) red[tid >> 6] = acc;
    __syncthreads();
    if (tid == 0) {
        float s = 0.0f;
        #pragma unroll
        for (int i = 0; i < kBlock / 64; ++i) s += red[i];
        partials[blk] = s;  // plain store, overwrites poison
    }
}

// ---------------------------------------------------------------------------
// Reduce 768 partials -> scalar loss. One block.
// ---------------------------------------------------------------------------
__global__ __launch_bounds__(kBlock) void reduce_kernel(
    const float* __restrict__ partials,
    float* __restrict__ out)
{
    __shared__ float red[kBlock / 64];
    const int tid = threadIdx.x;

    float acc = 0.0f;
    #pragma unroll
    for (int i = 0; i < kGridMain / kBlock; ++i)   // 3 each
        acc += partials[i * kBlock + tid];

    #pragma unroll
    for (int off = 32; off > 0; off >>= 1)
        acc += __shfl_down(acc, off, 64);
    if ((tid & 63) == 0) red[tid >> 6] = acc;
    __syncthreads();
    if (tid == 0) {
        float s = 0.0f;
        #pragma unroll
        for (int i = 0; i < kBlock / 64; ++i) s += red[i];
        out[0] = s * (1.0f / ((float)kCells * (float)kB));  // plain store
    }
}

extern "C" void kernel_launch(void* const* d_in, const int* in_sizes, int n_in,
                              void* d_out, int out_size, void* d_ws, size_t ws_size,
                              hipStream_t stream) {
    const float* output  = (const float*)d_in[0];
    const float* targets = (const float*)d_in[1];
    const float* anchors = (const float*)d_in[2];
    float* out = (float*)d_out;

    float* partials = (float*)d_ws;

    fused_kernel<<<dim3(kGridMain), dim3(kBlock), 0, stream>>>(
        output, targets, anchors, partials);
    reduce_kernel<<<dim3(1), dim3(kBlock), 0, stream>>>(partials, out);
}